// Round 11
// baseline (2240.538 us; speedup 1.0000x reference)
//
#include <hip/hip_runtime.h>
#include <math.h>

typedef unsigned short u16;
typedef __attribute__((ext_vector_type(8))) short frag8;   // 8 bf16 = 4 VGPR
typedef __attribute__((ext_vector_type(4))) float f32x4;   // MFMA acc

__device__ __forceinline__ float eluf(float v) { return v > 0.f ? v : expm1f(v); }
__device__ __forceinline__ float geluf(float v) {
  return 0.5f * v * (1.f + erff(v * 0.70710678118654752f));
}
__device__ __forceinline__ u16 f2bf(float f) {
  union { float f; unsigned int i; } v; v.f = f;
  return (u16)((v.i + 0x7fffu + ((v.i >> 16) & 1u)) >> 16);
}

#define BN_S 0.99999500003749969f   /* 1/sqrt(1+1e-5) */
#define NBLK 256

// manual grid barrier: counters zeroed per launch (captured memset), each
// sync point uses its own counter. Release/acquire fences on both sides
// (cross-XCD L2 non-coherence, Guideline 16).
__device__ __forceinline__ void gbar(int* cnt) {
  __threadfence();          // release: all threads flush prior writes
  __syncthreads();
  if (threadIdx.x == 0) {
    atomicAdd(cnt, 1);      // device-scope
    while (__hip_atomic_load(cnt, __ATOMIC_ACQUIRE, __HIP_MEMORY_SCOPE_AGENT) < NBLK)
      __builtin_amdgcn_s_sleep(2);
  }
  __syncthreads();
  __threadfence();          // acquire: invalidate stale cached lines
}

// ============================================================
// k_tws1 (unchanged)
// ============================================================
__global__ void k_tws1(const float* tw1, const float* tw2, const float* tw3, const float* tw4,
                       const float* tb1, const float* tb2, const float* tb3, const float* tb4,
                       const float* bn1g, const float* bn1b,
                       float* tws1, float* c1) {
  int idx = blockIdx.x * 256 + threadIdx.x;
  if (idx < 8320) {
    int i = idx / 65, u = idx - i * 65;
    int g = i >> 5, il = i & 31;
    const float* tws[4] = {tw1, tw2, tw3, tw4};
    const int P[4] = {7, 12, 25, 32};
    int c = u - 32;
    float s1 = bn1g[i] * BN_S;
    float val = 0.f;
    int p = P[g];
    if (c >= -p && c <= p) val = s1 * tws[g][il * (2 * p + 1) + (c + p)];
    tws1[idx] = val;
  } else if (idx < 8448) {
    int i = idx - 8320;
    int g = i >> 5, il = i & 31;
    const float* tbs[4] = {tb1, tb2, tb3, tb4};
    float s1 = bn1g[i] * BN_S;
    c1[i] = s1 * tbs[g][il] + bn1b[i];
  }
}

// ============================================================
// k_weff (unchanged from r6)
// ============================================================
__global__ __launch_bounds__(256) void k_weff(const float* __restrict__ sw, const float* __restrict__ sb,
                                              const float* __restrict__ tws1, const float* __restrict__ c1,
                                              u16* __restrict__ Wb, float* __restrict__ biasEff) {
  const int lane = threadIdx.x & 63, wave = threadIdx.x >> 6;
  const int u = blockIdx.x;
  const int o = blockIdx.y * 4 + wave;
  const float* swp = sw + o * 8192 + lane;
  if (u < 65) {
    const float* tp = tws1 + u;
    float a0 = 0.f, a1 = 0.f, a2 = 0.f, a3 = 0.f;
    #pragma unroll 8
    for (int i = 0; i < 128; i += 4) {
      a0 = fmaf(swp[(i + 0) * 64], tp[(i + 0) * 65], a0);
      a1 = fmaf(swp[(i + 1) * 64], tp[(i + 1) * 65], a1);
      a2 = fmaf(swp[(i + 2) * 64], tp[(i + 2) * 65], a2);
      a3 = fmaf(swp[(i + 3) * 64], tp[(i + 3) * 65], a3);
    }
    Wb[(u * 128 + o) * 64 + lane] = f2bf((a0 + a1) + (a2 + a3));
  } else {
    float pa = 0.f;
    #pragma unroll 8
    for (int i = 0; i < 128; i++)
      pa = fmaf(swp[i * 64], c1[i], pa);
    #pragma unroll
    for (int off = 32; off; off >>= 1) pa += __shfl_xor(pa, off);
    if (lane == 0) biasEff[o] = pa + sb[o];
  }
}

// ============================================================
// k_conv (MFMA, unchanged from r4)
// ============================================================
__global__ __launch_bounds__(256) void k_conv(const float* __restrict__ x,
                                              const u16* __restrict__ Wb,
                                              const float* __restrict__ biasEff,
                                              const float* __restrict__ bn2g, const float* __restrict__ bn2b,
                                              float* __restrict__ z) {
  __shared__ u16 xs[128 * 88];
  const int tid = threadIdx.x;
  const int t0 = blockIdx.x * 64;
  const int o0 = blockIdx.y * 64;
  const int b  = blockIdx.z;

  #pragma unroll
  for (int i = 0; i < 8; i++) {
    int pos = tid + i * 256;
    int kh = pos >> 5;
    int tt = (pos & 31) * 4;
    int gt = t0 - 32 + tt;
    const float* xp = x + (b * 64 + kh) * 1000;
    float v[4];
    if (gt >= 0 && gt + 3 < 1000) {
      float4 f = *(const float4*)(xp + gt);
      v[0] = f.x; v[1] = f.y; v[2] = f.z; v[3] = f.w;
    } else {
      #pragma unroll
      for (int e = 0; e < 4; e++) { int g2 = gt + e; v[e] = (g2 >= 0 && g2 < 1000) ? xp[g2] : 0.f; }
    }
    #pragma unroll
    for (int e = 0; e < 4; e++) xs[(tt + e) * 88 + kh] = f2bf(v[e]);
  }
  __syncthreads();

  const int lane = tid & 63, wave = tid >> 6;
  const int wt = (wave & 1) * 32;
  const int wo = (wave >> 1) * 32;
  const int m = lane & 15, q = lane >> 4;

  f32x4 acc[2][2];
  #pragma unroll
  for (int i = 0; i < 2; i++)
    #pragma unroll
    for (int j = 0; j < 2; j++) acc[i][j] = (f32x4){0.f, 0.f, 0.f, 0.f};

  #pragma unroll 2
  for (int u = 0; u < 65; u++) {
    frag8 A[2][2], B[2][2];
    #pragma unroll
    for (int tp = 0; tp < 2; tp++)
      #pragma unroll
      for (int kc = 0; kc < 2; kc++)
        A[tp][kc] = *(const frag8*)&xs[(wt + tp * 16 + m + u) * 88 + kc * 32 + q * 8];
    #pragma unroll
    for (int op = 0; op < 2; op++)
      #pragma unroll
      for (int kc = 0; kc < 2; kc++)
        B[op][kc] = *(const frag8*)(Wb + ((u * 128) + o0 + wo + op * 16 + m) * 64 + kc * 32 + q * 8);
    #pragma unroll
    for (int tp = 0; tp < 2; tp++)
      #pragma unroll
      for (int op = 0; op < 2; op++) {
        acc[tp][op] = __builtin_amdgcn_mfma_f32_16x16x32_bf16(A[tp][0], B[op][0], acc[tp][op], 0, 0, 0);
        acc[tp][op] = __builtin_amdgcn_mfma_f32_16x16x32_bf16(A[tp][1], B[op][1], acc[tp][op], 0, 0, 0);
      }
  }

  #pragma unroll
  for (int op = 0; op < 2; op++) {
    int o = o0 + wo + op * 16 + m;
    float s2 = bn2g[o] * BN_S;
    float be = biasEff[o], b2 = bn2b[o];
    #pragma unroll
    for (int tp = 0; tp < 2; tp++) {
      #pragma unroll
      for (int r = 0; r < 4; r++) {
        int t = t0 + wt + tp * 16 + q * 4 + r;
        if (t < 1000)
          z[(b * 128 + o) * 1000 + t] = eluf((acc[tp][op][r] + be) * s2 + b2);
      }
    }
  }
}

// ============================================================
// k_pool (unchanged)
// ============================================================
__global__ __launch_bounds__(128) void k_pool(const float* __restrict__ z, float* __restrict__ X) {
  int p = blockIdx.x, b = blockIdx.y, o = threadIdx.x;
  const float* zp = z + (b * 128 + o) * 1000 + p * 15;
  float s = 0.f, ss = 0.f;
  #pragma unroll
  for (int k = 0; k < 50; k++) { float v = zp[k]; s += v; ss = fmaf(v, v, ss); }
  float m = s * 0.02f;
  float var = (ss - s * m) * (1.f / 49.f);
  var = fminf(fmaxf(var, 1e-6f), 1e6f);
  X[(b * 64 + p) * 128 + o] = m;
  X[((16 + b) * 64 + p) * 128 + o] = logf(var);
}

// ============================================================
// mgemm_tile: one 64(m) x 64(n) tile of C = act(LN?(A) @ W^T + bias) (+R).
// Verbatim r6-verified k_mgemm body as a block-level device function.
// smem: As u16[64*136] @0, Ws u16[64*136] @17408, mS @34816, rS @35072.
// ============================================================
__device__ __forceinline__ void mgemm_tile(
    const float* __restrict__ A, const float* __restrict__ W,
    const float* __restrict__ bias, float* __restrict__ C,
    const float* __restrict__ R,
    const float* __restrict__ lng, const float* __restrict__ lnb,
    int m0, int nloc, int nper, int K, int act, char* smem) {
  u16* As = (u16*)smem;
  u16* Ws = (u16*)(smem + 17408);
  float* mS = (float*)(smem + 34816);
  float* rS = (float*)(smem + 35072);
  const int tid = threadIdx.x;
  const int lane = tid & 63, wave = tid >> 6;

  if (lng) {   // row stats (K==128)
    #pragma unroll 1
    for (int rr = 0; rr < 16; rr++) {
      int r = wave * 16 + rr;
      const float* ap = A + (m0 + r) * 128;
      float v0 = ap[lane], v1 = ap[64 + lane];
      float s = v0 + v1;
      #pragma unroll
      for (int off = 32; off; off >>= 1) s += __shfl_xor(s, off);
      float mn = s * (1.f / 128.f);
      float d0 = v0 - mn, d1 = v1 - mn;
      float qq = d0 * d0 + d1 * d1;
      #pragma unroll
      for (int off = 32; off; off >>= 1) qq += __shfl_xor(qq, off);
      if (lane == 0) { mS[r] = mn; rS[r] = rsqrtf(qq * (1.f / 128.f) + 1e-5f); }
    }
  }

  const int m = lane & 15, q = lane >> 4;
  const int wt = (wave & 1) * 32, wn = (wave >> 1) * 32;
  f32x4 acc[2][2];
  #pragma unroll
  for (int i = 0; i < 2; i++)
    #pragma unroll
    for (int j = 0; j < 2; j++) acc[i][j] = (f32x4){0, 0, 0, 0};

  for (int k0 = 0; k0 < K; k0 += 128) {
    __syncthreads();
    #pragma unroll
    for (int i = 0; i < 8; i++) {
      int pos = tid + i * 256;
      int row = pos >> 5;
      int c4 = (pos & 31) * 4;
      float4 av = *(const float4*)(A + (m0 + row) * K + k0 + c4);
      if (lng) {
        float mn = mS[row], rs = rS[row];
        av.x = (av.x - mn) * rs * lng[c4 + 0] + lnb[c4 + 0];
        av.y = (av.y - mn) * rs * lng[c4 + 1] + lnb[c4 + 1];
        av.z = (av.z - mn) * rs * lng[c4 + 2] + lnb[c4 + 2];
        av.w = (av.w - mn) * rs * lng[c4 + 3] + lnb[c4 + 3];
      }
      u16* ap = As + row * 136 + c4;
      ap[0] = f2bf(av.x); ap[1] = f2bf(av.y); ap[2] = f2bf(av.z); ap[3] = f2bf(av.w);
      float4 wv = *(const float4*)(W + (nloc + row) * K + k0 + c4);
      u16* wp = Ws + row * 136 + c4;
      wp[0] = f2bf(wv.x); wp[1] = f2bf(wv.y); wp[2] = f2bf(wv.z); wp[3] = f2bf(wv.w);
    }
    __syncthreads();
    #pragma unroll
    for (int kc = 0; kc < 4; kc++) {
      frag8 Af[2], Bf[2];
      #pragma unroll
      for (int tp = 0; tp < 2; tp++)
        Af[tp] = *(const frag8*)&As[(wt + tp * 16 + m) * 136 + kc * 32 + q * 8];
      #pragma unroll
      for (int np = 0; np < 2; np++)
        Bf[np] = *(const frag8*)&Ws[(wn + np * 16 + m) * 136 + kc * 32 + q * 8];
      #pragma unroll
      for (int tp = 0; tp < 2; tp++)
        #pragma unroll
        for (int np = 0; np < 2; np++)
          acc[tp][np] = __builtin_amdgcn_mfma_f32_16x16x32_bf16(Af[tp], Bf[np], acc[tp][np], 0, 0, 0);
    }
  }

  #pragma unroll
  for (int np = 0; np < 2; np++) {
    int col = nloc + wn + np * 16 + m;
    float bv = bias[col];
    #pragma unroll
    for (int tp = 0; tp < 2; tp++) {
      #pragma unroll
      for (int r = 0; r < 4; r++) {
        int mrow = m0 + wt + tp * 16 + q * 4 + r;
        float v = acc[tp][np][r] + bv;
        if (act == 1) v = geluf(v);
        if (R) v += R[mrow * nper + col];
        C[mrow * nper + col] = v;
      }
    }
  }
}

// ============================================================
// k_encp: persistent 4-layer encoder, 256 blocks, manual grid barrier.
// Stage bodies identical to r10 (r6-verified math).
// ============================================================
__global__ __launch_bounds__(256, 2) void k_encp(
    float* __restrict__ X,
    const float* __restrict__ ln1g, const float* __restrict__ ln1b,
    const float* __restrict__ ln2g, const float* __restrict__ ln2b,
    const float* __restrict__ wq, const float* __restrict__ bq,
    const float* __restrict__ wk, const float* __restrict__ bk,
    const float* __restrict__ wv, const float* __restrict__ bv,
    const float* __restrict__ wo, const float* __restrict__ bo,
    const float* __restrict__ f1w, const float* __restrict__ f1b,
    const float* __restrict__ f2w, const float* __restrict__ f2b,
    float* __restrict__ Qb, float* __restrict__ Kb, float* __restrict__ Vb,
    float* __restrict__ AO, float* __restrict__ F1, int* __restrict__ bar) {
  __shared__ __align__(16) char smem[35328];
  const int b = blockIdx.x;

  for (int l = 0; l < 4; l++) {
    int* c = bar + l * 5;
    // ---- Stage 1: LN1 + QKV (192 tile-tasks) ----
    if (b < 192) {
      int m0 = (b & 31) * 64;
      int n0 = (b >> 5) * 64;           // 0..320
      int p = n0 >> 7;                  // 0=Q 1=K 2=V
      int nloc = n0 & 127;
      const float* Wp = (p == 0 ? wq : p == 1 ? wk : wv) + l * 16384;
      const float* bp = (p == 0 ? bq : p == 1 ? bk : bv) + l * 128;
      float* Cp = (p == 0 ? Qb : p == 1 ? Kb : Vb);
      mgemm_tile(X, Wp, bp, Cp, nullptr, ln1g + l * 128, ln1b + l * 128,
                 m0, nloc, 128, 128, 0, smem);
    }
    gbar(c + 0);
    // ---- Stage 2: attention (256 wave-tasks on blocks 0..63) ----
    if (b < 64) {
      const int wv_ = threadIdx.x >> 6;
      const int lane = threadIdx.x & 63;
      const int task = b * 4 + wv_;
      const int bb = task >> 3, h = task & 7;
      float* KsW = (float*)smem + wv_ * 2048;
      float* VsW = KsW + 1024;
      const int base = (bb * 64) * 128 + h * 16;
      for (int idx = lane; idx < 1024; idx += 64) {
        int n = idx >> 4, j = idx & 15;
        KsW[idx] = Kb[base + n * 128 + j];
        VsW[idx] = Vb[base + n * 128 + j];
      }
      __syncthreads();
      float qv[16];
      #pragma unroll
      for (int j = 0; j < 16; j++) qv[j] = Qb[base + lane * 128 + j];
      float mrun = -1e30f, lrun = 0.f, o[16];
      #pragma unroll
      for (int j = 0; j < 16; j++) o[j] = 0.f;
      for (int k = 0; k < 64; k++) {
        float s = 0.f;
        #pragma unroll
        for (int j = 0; j < 16; j++) s = fmaf(qv[j], KsW[k * 16 + j], s);
        s *= 0.25f;
        float mnew = fmaxf(mrun, s);
        float corr = __expf(mrun - mnew);
        float p = __expf(s - mnew);
        lrun = lrun * corr + p;
        #pragma unroll
        for (int j = 0; j < 16; j++) o[j] = fmaf(o[j], corr, p * VsW[k * 16 + j]);
        mrun = mnew;
      }
      float inv = 1.f / lrun;
      #pragma unroll
      for (int j = 0; j < 16; j++) AO[base + lane * 128 + j] = o[j] * inv;
    }
    gbar(c + 1);
    // ---- Stage 3: O-proj + residual (64 tile-tasks) ----
    if (b < 64) {
      int m0 = (b & 31) * 64;
      int n0 = (b >> 5) * 64;
      mgemm_tile(AO, wo + l * 16384, bo + l * 128, X, X, nullptr, nullptr,
                 m0, n0, 128, 128, 0, smem);
    }
    gbar(c + 2);
    // ---- Stage 4: LN2 + F1 + gelu (256 tile-tasks) ----
    {
      int m0 = (b & 31) * 64;
      int n0 = (b >> 5) * 64;           // 0..448
      mgemm_tile(X, f1w + l * 65536, f1b + l * 512, F1, nullptr,
                 ln2g + l * 128, ln2b + l * 128, m0, n0, 512, 128, 1, smem);
    }
    gbar(c + 3);
    // ---- Stage 5: F2 + residual (64 tile-tasks, K=512) ----
    if (b < 64) {
      int m0 = (b & 31) * 64;
      int n0 = (b >> 5) * 64;
      mgemm_tile(F1, f2w + l * 65536, f2b + l * 128, X, X, nullptr, nullptr,
                 m0, n0, 128, 512, 0, smem);
    }
    gbar(c + 4);
  }
}

// ============================================================
// k_head1 / k_head2 (unchanged)
// ============================================================
__global__ __launch_bounds__(256) void k_head1(const float* __restrict__ X, const float* __restrict__ ew,
                                               const float* __restrict__ eb, const float* __restrict__ g3,
                                               const float* __restrict__ b3, float* __restrict__ G) {
  __shared__ float Xs[2][8192];
  int b = blockIdx.x, ot = blockIdx.y;
  int tid = threadIdx.x;
  {
    const float4* x1 = (const float4*)(X + b * 8192);
    const float4* x2 = (const float4*)(X + (16 + b) * 8192);
    float4* s1 = (float4*)&Xs[0][0];
    float4* s2 = (float4*)&Xs[1][0];
    for (int i = tid; i < 2048; i += 256) { s1[i] = x1[i]; s2[i] = x2[i]; }
  }
  __syncthreads();
  int w = tid & 127, og = tid >> 7;
  int oc0 = ot * 16 + og * 8;
  float a[8] = {};
  for (int ic = 0; ic < 64; ic++) {
    float x1v = Xs[0][ic * 128 + w], x2v = Xs[1][ic * 128 + w];
    #pragma unroll
    for (int j = 0; j < 8; j++) {
      a[j] = fmaf(ew[((oc0 + j) * 64 + ic) * 2 + 0], x1v, a[j]);
      a[j] = fmaf(ew[((oc0 + j) * 64 + ic) * 2 + 1], x2v, a[j]);
    }
  }
  #pragma unroll
  for (int j = 0; j < 8; j++) {
    int oc = oc0 + j;
    float v = (a[j] + eb[oc]) * (g3[oc] * BN_S) + b3[oc];
    G[(b * 64 + oc) * 128 + w] = eluf(v);
  }
}

__global__ __launch_bounds__(256) void k_head2(const float* __restrict__ G, const float* __restrict__ cw,
                                               const float* __restrict__ cb, float* __restrict__ out) {
  __shared__ float red[256];
  int b = blockIdx.x, c = blockIdx.y, tid = threadIdx.x;
  const float4* g4 = (const float4*)(G + b * 8192);
  const float4* c4 = (const float4*)(cw + c * 8192);
  float p = 0.f;
  for (int i = tid; i < 2048; i += 256) {
    float4 g = g4[i], w = c4[i];
    p += g.x * w.x + g.y * w.y + g.z * w.z + g.w * w.w;
  }
  red[tid] = p;
  __syncthreads();
  for (int s = 128; s > 0; s >>= 1) {
    if (tid < s) red[tid] += red[tid + s];
    __syncthreads();
  }
  if (tid == 0) out[b * 4 + c] = red[0] + cb[c];
}

// ============================================================
extern "C" void kernel_launch(void* const* d_in, const int* in_sizes, int n_in,
                              void* d_out, int out_size, void* d_ws, size_t ws_size,
                              hipStream_t stream) {
  const float* x    = (const float*)d_in[0];
  const float* tw1  = (const float*)d_in[1];  const float* tb1 = (const float*)d_in[2];
  const float* tw2  = (const float*)d_in[3];  const float* tb2 = (const float*)d_in[4];
  const float* tw3  = (const float*)d_in[5];  const float* tb3 = (const float*)d_in[6];
  const float* tw4  = (const float*)d_in[7];  const float* tb4 = (const float*)d_in[8];
  const float* bn1g = (const float*)d_in[9];  const float* bn1b = (const float*)d_in[10];
  const float* sw   = (const float*)d_in[11]; const float* sb   = (const float*)d_in[12];
  const float* bn2g = (const float*)d_in[13]; const float* bn2b = (const float*)d_in[14];
  const float* ln1g = (const float*)d_in[15]; const float* ln1b = (const float*)d_in[16];
  const float* ln2g = (const float*)d_in[17]; const float* ln2b = (const float*)d_in[18];
  const float* wq   = (const float*)d_in[19]; const float* bq   = (const float*)d_in[20];
  const float* wk   = (const float*)d_in[21]; const float* bk   = (const float*)d_in[22];
  const float* wv   = (const float*)d_in[23]; const float* bv   = (const float*)d_in[24];
  const float* wo   = (const float*)d_in[25]; const float* bo   = (const float*)d_in[26];
  const float* f1w  = (const float*)d_in[27]; const float* f1b  = (const float*)d_in[28];
  const float* f2w  = (const float*)d_in[29]; const float* f2b  = (const float*)d_in[30];
  const float* ew   = (const float*)d_in[31]; const float* eb   = (const float*)d_in[32];
  const float* g3   = (const float*)d_in[33]; const float* b3   = (const float*)d_in[34];
  const float* cw   = (const float*)d_in[35]; const float* cb   = (const float*)d_in[36];

  float* ws      = (float*)d_ws;
  float* tws1    = ws;               // 8320 (dead after k_weff; barrier counters reuse ws[0..20])
  float* c1      = ws + 8320;        // 128
  float* biasEff = ws + 8448;        // 128
  u16*   Wb      = (u16*)(ws + 8576);// 532480 bf16 [u][o][kh]
  float* z       = ws + 541056;      // 2048000 [b][o][t]; reused as G after pool
  float* X       = ws + 2589056;     // 262144  [2048][128]
  float* Qb      = ws + 3113344;     // 262144
  float* Kb      = ws + 3375488;     // 262144
  float* Vb      = ws + 3637632;     // 262144
  float* AO      = ws + 3899776;     // 262144
  float* F1      = ws + 4161920;     // 1048576 [2048][512]
  float* G       = z;
  int*   bar     = (int*)ws;         // 20 counters, aliases dead tws1 region

  k_tws1<<<33, 256, 0, stream>>>(tw1, tw2, tw3, tw4, tb1, tb2, tb3, tb4, bn1g, bn1b, tws1, c1);
  k_weff<<<dim3(66, 32), 256, 0, stream>>>(sw, sb, tws1, c1, Wb, biasEff);
  k_conv<<<dim3(16, 2, 16), 256, 0, stream>>>(x, Wb, biasEff, bn2g, bn2b, z);
  k_pool<<<dim3(64, 16), 128, 0, stream>>>(z, X);

  // zero barrier counters (tws1 region is dead by now); captured as a memset node
  hipMemsetAsync(bar, 0, 20 * sizeof(int), stream);

  k_encp<<<NBLK, 256, 0, stream>>>(X, ln1g, ln1b, ln2g, ln2b,
                                   wq, bq, wk, bk, wv, bv, wo, bo,
                                   f1w, f1b, f2w, f2b,
                                   Qb, Kb, Vb, AO, F1, bar);

  k_head1<<<dim3(16, 4), 256, 0, stream>>>(X, ew, eb, g3, b3, G);
  k_head2<<<dim3(16, 4), 256, 0, stream>>>(G, cw, cb, (float*)d_out);
}